// Round 1
// baseline (524.837 us; speedup 1.0000x reference)
//
#include <hip/hip_runtime.h>
#include <hip/hip_bf16.h>

// DownSamplingSpatial2Channel == gathered GEMM:
//   out[m,o] = sum_k in_data[inv[m*8 + k/32], k%32] * Wf[k,o]
//   Wf[s*32+j, o] = sum_c W_mid[j,c] * W_out[s*32+c, o]
// M = 262144, K = 256, N = 256. HBM-bound (A fp32 268MB + out fp32 268MB).

typedef short bf16x8 __attribute__((ext_vector_type(8)));
typedef float f32x4 __attribute__((ext_vector_type(4)));

__device__ __forceinline__ unsigned short f2bf(float f) {
    union { float f; unsigned u; } x; x.f = f;
    unsigned u = x.u;
    u += 0x7fffu + ((u >> 16) & 1u);   // round-to-nearest-even
    return (unsigned short)(u >> 16);
}

// Wt[o][k] = sum_c W_mid[k%32, c] * W_out[(k/32)*32 + c, o]   (bf16, transposed)
__global__ void build_wf(const float* __restrict__ Wmid,
                         const float* __restrict__ Wout,
                         unsigned short* __restrict__ Wt) {
    const int o = blockIdx.x;      // output channel, 0..255
    const int k = threadIdx.x;     // fused-K index, 0..255
    const int s = k >> 5;
    const int j = k & 31;
    float acc = 0.f;
#pragma unroll
    for (int c = 0; c < 32; ++c)
        acc += Wmid[j * 32 + c] * Wout[(s * 32 + c) * 256 + o];
    Wt[o * 256 + k] = f2bf(acc);
}

// inv[down*8 + local] = fine-row index (flat_idx is a permutation)
__global__ void build_inv(const int* __restrict__ ijk,
                          const int* __restrict__ down,
                          int* __restrict__ inv, int n) {
    int i = blockIdx.x * 256 + threadIdx.x;
    if (i < n) {
        int a = ijk[3 * i], b = ijk[3 * i + 1], c = ijk[3 * i + 2];
        int ls = ((a & 1) << 2) | ((b & 1) << 1) | (c & 1);   // s_factor = 2
        inv[down[i] * 8 + ls] = i;
    }
}

// One block: 64(M) x 256(N) output tile. 4 waves, each 64(M) x 64(N).
// K-loop: 8 steps of BK=32 (each step is exactly one s-block of the gather).
__global__ __launch_bounds__(256) void gemm_fused(
    const float* __restrict__ A,            // in_data (N_fine x 32) fp32
    const int* __restrict__ inv,            // (M*8) permutation inverse
    const unsigned short* __restrict__ Wt,  // (256 x 256) bf16, [o][k]
    float* __restrict__ out)                // (M x 256) fp32
{
    __shared__ int invS[512];
    __shared__ __align__(16) unsigned short Abuf[64 * 32];    // [row][k] bf16, 4KB
    __shared__ __align__(16) unsigned short Bbuf[256 * 32];   // [o][k]   bf16, 16KB

    const int t = threadIdx.x;
    const long m0 = (long)blockIdx.x * 64;

    // inv entries for this block's 64 coarse rows: contiguous 512 ints
    invS[t]       = inv[m0 * 8 + t];
    invS[256 + t] = inv[m0 * 8 + 256 + t];

    const int wave = t >> 6;
    const int lane = t & 63;
    const int q    = lane >> 4;    // quad 0..3
    const int r16  = lane & 15;

    f32x4 acc[4][4];
#pragma unroll
    for (int i = 0; i < 4; ++i)
#pragma unroll
        for (int j = 0; j < 4; ++j)
            acc[i][j] = (f32x4){0.f, 0.f, 0.f, 0.f};

    __syncthreads();   // invS ready

    for (int kb = 0; kb < 8; ++kb) {
        // ---- stage A: 64 rows x 32 cols, gathered fp32 -> bf16 ----
        // 512 float4 segments total; 2 per thread; 8 lanes cover one 128B row.
#pragma unroll
        for (int i = 0; i < 2; ++i) {
            int flat = t + i * 256;          // 0..511
            int row  = flat >> 3;
            int seg  = flat & 7;
            long g   = invS[row * 8 + kb];
            const float4 v = *(const float4*)(A + g * 32 + seg * 4);
            ushort4 b;
            b.x = f2bf(v.x); b.y = f2bf(v.y); b.z = f2bf(v.z); b.w = f2bf(v.w);
            *(ushort4*)(&Abuf[row * 32 + seg * 4]) = b;
        }
        // ---- stage B: 256 rows x 32 cols bf16 from Wt (L2-resident) ----
#pragma unroll
        for (int i = 0; i < 4; ++i) {
            int c = t + i * 256;             // 16B chunk id, 0..1023
            int o = c >> 2;
            int seg = c & 3;
            *(int4*)(&Bbuf[o * 32 + seg * 8]) =
                *(const int4*)(Wt + (long)o * 256 + kb * 32 + seg * 8);
        }
        __syncthreads();

        // ---- fragments + MFMA ----
        bf16x8 af[4], bfr[4];
#pragma unroll
        for (int mt = 0; mt < 4; ++mt)
            af[mt] = *(const bf16x8*)(&Abuf[(mt * 16 + r16) * 32 + q * 8]);
#pragma unroll
        for (int nt = 0; nt < 4; ++nt)
            bfr[nt] = *(const bf16x8*)(&Bbuf[(wave * 64 + nt * 16 + r16) * 32 + q * 8]);
#pragma unroll
        for (int mt = 0; mt < 4; ++mt)
#pragma unroll
            for (int nt = 0; nt < 4; ++nt)
                acc[mt][nt] = __builtin_amdgcn_mfma_f32_16x16x32_bf16(
                    af[mt], bfr[nt], acc[mt][nt], 0, 0, 0);
        __syncthreads();
    }

    // ---- epilogue: C/D layout col=lane&15, row=(lane>>4)*4+reg ----
#pragma unroll
    for (int mt = 0; mt < 4; ++mt)
#pragma unroll
        for (int nt = 0; nt < 4; ++nt)
#pragma unroll
            for (int rg = 0; rg < 4; ++rg) {
                int row = mt * 16 + q * 4 + rg;
                int col = wave * 64 + nt * 16 + r16;
                out[(m0 + row) * 256 + col] = acc[mt][nt][rg];
            }
}

extern "C" void kernel_launch(void* const* d_in, const int* in_sizes, int n_in,
                              void* d_out, int out_size, void* d_ws, size_t ws_size,
                              hipStream_t stream) {
    const float* in_data = (const float*)d_in[0];
    const float* W_mid   = (const float*)d_in[1];
    const float* W_out   = (const float*)d_in[2];
    const int*   ijk     = (const int*)d_in[3];
    const int*   down    = (const int*)d_in[4];

    const int Nf = in_sizes[0] / 32;   // fine voxels (2,097,152)
    const int M  = Nf / 8;             // coarse voxels (262,144)

    unsigned short* Wt = (unsigned short*)d_ws;          // 256*256 bf16 = 128KB
    int* inv = (int*)((char*)d_ws + 131072);             // Nf ints = 8MB

    build_wf<<<256, 256, 0, stream>>>(W_mid, W_out, Wt);
    build_inv<<<(Nf + 255) / 256, 256, 0, stream>>>(ijk, down, inv, Nf);
    gemm_fused<<<M / 64, 256, 0, stream>>>(in_data, inv, Wt, (float*)d_out);
}